// Round 5
// baseline (783.133 us; speedup 1.0000x reference)
//
#include <hip/hip_runtime.h>

#define NN 100000
#define NE 1600000
#define WT 12
#define CI 16
#define CM 32
#define CO 32

#define FXS 33554432.0f   // 2^25 fixed-point scale for deg

typedef float f32x4 __attribute__((ext_vector_type(4)));  // native vec for nontemporal builtin

// ---- bf16 pack (round-to-nearest-even), 2 channels per uint ---------------
__device__ __forceinline__ unsigned bf16pack(float a, float b) {
    unsigned ua = __float_as_uint(a);
    unsigned ub = __float_as_uint(b);
    ua = (ua + 0x7FFFu + ((ua >> 16) & 1u)) >> 16;
    ub = (ub + 0x7FFFu + ((ub >> 16) & 1u)) >> 16;
    return ua | (ub << 16);
}

// ---------------- K0: transpose x [t][n][ci] -> xTb [n][96 uints] ----------
__global__ void k_xpose(const float* __restrict__ x, unsigned* __restrict__ xTb) {
    int f = blockIdx.x * 256 + threadIdx.x;            // over NN*96
    if (f >= NN * 96) return;
    int n = f / 96;
    int u = f - n * 96;
    int t = u >> 3;
    int p = u & 7;
    const float2* x2 = (const float2*)x;
    float2 v = x2[((size_t)t * NN + n) * 8 + p];
    xTb[f] = bf16pack(v.x, v.y);
}

// ---------------- K1: ONE packed 64-bit atomic per edge --------------------
// pk[c] bits 40+: count; bits 0..39: fixed-point weighted degree (ew * 2^25).
// Returned old value gives this edge's rank within its destination.
__global__ void k_count(const int* __restrict__ A, const float* __restrict__ ew,
                        unsigned long long* __restrict__ pk, int* __restrict__ rank) {
    int e = blockIdx.x * 256 + threadIdx.x;
    if (e >= NE) return;
    int c = A[NE + e];
    unsigned long long fx = (unsigned long long)(ew[e] * FXS + 0.5f);
    unsigned long long old = atomicAdd(&pk[c], (1ull << 40) | fx);
    rank[e] = (int)(old >> 40);
}

// ---------------- K2: dis = rsqrt(deg), segment allocation (wave-scan) -----
// ds[n] = {start, cnt}; dis[n] = deg>0 ? rsqrt(deg) : 0
__global__ void k_dis_alloc(const unsigned long long* __restrict__ pk,
                            float* __restrict__ dis, int2* __restrict__ ds,
                            int* __restrict__ total) {
    int n = blockIdx.x * 256 + threadIdx.x;
    bool valid = (n < NN);
    int c = 0;
    if (valid) {
        unsigned long long v = pk[n];
        c = (int)(v >> 40);
        float d = (float)(v & ((1ull << 40) - 1)) * (1.0f / FXS);
        dis[n] = d > 0.0f ? rsqrtf(d) : 0.0f;
    }
    int lane = threadIdx.x & 63;
    int inc = c;
    #pragma unroll
    for (int o = 1; o < 64; o <<= 1) {
        int v = __shfl_up(inc, o, 64);
        if (lane >= o) inc += v;
    }
    int base = 0;
    if (lane == 63) base = atomicAdd(total, inc);   // one atomic per wave
    base = __shfl(base, 63, 64);
    if (valid) ds[n] = make_int2(base + inc - c, c);
}

// ---------------- K3: atomic-free scatter ----------------------------------
// meta[p] = {src, dis[src]*ew}; dis[dst] applied at end of k_agg instead.
__global__ void k_scatter(const int* __restrict__ A, const float* __restrict__ ew,
                          const float* __restrict__ dis, const int2* __restrict__ ds,
                          const int* __restrict__ rank, float2* __restrict__ meta) {
    int e = blockIdx.x * 256 + threadIdx.x;
    if (e >= NE) return;
    int r = A[e];
    int c = A[NE + e];
    float w = dis[r] * ew[e];
    int p = ds[c].x + rank[e];
    meta[p] = make_float2(__int_as_float(r), w);
}

// ---------------- K4: aggregation, one wave per dst node -------------------
// Lane l<48 loads uint2 -> whole 384B bf16 row in ONE coalesced dwordx2.
// 4 fp32 accs/lane (flat channels 4l..4l+3); dis[node] applied once at end.
__global__ __launch_bounds__(256) void k_agg(const unsigned* __restrict__ xTb,
                      const int2* __restrict__ ds, const float* __restrict__ dis,
                      const float2* __restrict__ meta, float* __restrict__ xagg) {
    int wave = threadIdx.x >> 6;
    int lane = threadIdx.x & 63;
    int node = blockIdx.x * 4 + wave;
    int2 sc = ds[node];
    int s = __builtin_amdgcn_readfirstlane(sc.x);   // force scalar -> s_load meta
    int c = __builtin_amdgcn_readfirstlane(sc.y);
    int li = lane < 48 ? lane : 47;                 // clamp: same cache line, no branch
    float4 acc = make_float4(0.f, 0.f, 0.f, 0.f);
    const float2* mp = meta + s;
    #pragma unroll 4
    for (int i = 0; i < c; i++) {
        float2 m = mp[i];                           // wave-uniform -> scalar load
        int src = __float_as_int(m.x);
        float w = m.y;
        uint2 u = ((const uint2*)(xTb + (size_t)src * 96))[li];
        acc.x += w * __uint_as_float(u.x << 16);
        acc.y += w * __uint_as_float(u.x & 0xFFFF0000u);
        acc.z += w * __uint_as_float(u.y << 16);
        acc.w += w * __uint_as_float(u.y & 0xFFFF0000u);
    }
    float dn = dis[node];
    acc.x *= dn; acc.y *= dn; acc.z *= dn; acc.w *= dn;
    if (lane < 48)
        ((float4*)(xagg + (size_t)node * 192))[lane] = acc;
}

// ---------------- K5a: fold GCN weight into conv weight --------------------
__global__ void k_foldW(const float* __restrict__ gw, const float* __restrict__ cw,
                        float* __restrict__ M2) {
    int i = blockIdx.x * 256 + threadIdx.x;
    if (i >= WT * 3 * CI * CO) return;
    int co = i & 31;
    int rem = i >> 5;            // t*48 + k*16 + ci
    int ci = rem & 15;
    int kidx = rem % 48;
    int k = kidx >> 4;
    int t = rem / 48;
    int tp = t + k - 1;
    float s = 0.0f;
    if (tp >= 0 && tp < WT) {
        for (int cm = 0; cm < CM; cm++)
            s += gw[(tp * CI + ci) * CM + cm] * cw[co * (CM * 3) + cm * 3 + k];
    }
    M2[i] = s;
}

// ---------------- K5b: fold biases -----------------------------------------
__global__ void k_foldB(const float* __restrict__ gb, const float* __restrict__ cw,
                        const float* __restrict__ cb, float* __restrict__ B2) {
    int i = blockIdx.x * 256 + threadIdx.x;
    if (i >= WT * CO) return;
    int co = i & 31;
    int t = i >> 5;
    float s = cb[co];
    for (int k = 0; k < 3; k++) {
        int tp = t + k - 1;
        if (tp < 0 || tp >= WT) continue;
        for (int cm = 0; cm < CM; cm++)
            s += gb[tp * CM + cm] * cw[co * (CM * 3) + cm * 3 + k];
    }
    B2[i] = s;
}

// ---------------- K7: per-(chunk,t) epilogue, XCD-swizzled 1D grid ---------
// Grid = 392 chunks x 12 t = 4704 blocks (%8==0). chunk/t decoded from a
// SWIZZLED block id -> block-uniform -> weights stay s_load (SGPR 112).
// Swizzle: wgid=(bid&7)*588+(bid>>3): each XCD gets a contiguous wgid range
// with t fastest -> the 12 sharers of one 192KB xagg chunk run back-to-back
// on ONE XCD -> re-reads are L2-hits, HBM fetch compulsory (53MB, round 3).
// All 12 xagg float4 loads hoisted into xa[12] BEFORE any FMA. Round-3's
// VGPR=40 proved the compiler serialized them (~2 in flight, vmcnt-latency-
// bound: VALUBusy 29%, occupancy 49%, 102us). Staging costs ~48 VGPR ->
// ~1 vmcnt wait total, then a clean 48x32 FMA sweep with weight s_loads
// pipelining underneath. out stores nontemporal: the 154MB output stream
// must not evict the xagg lines neighbor-t blocks re-read.
__global__ __launch_bounds__(256) void k_out(const float* __restrict__ xagg,
                                             const float* __restrict__ M2,
                                             const float* __restrict__ B2,
                                             float* __restrict__ out) {
    int wgid  = ((int)blockIdx.x & 7) * 588 + ((int)blockIdx.x >> 3);
    int chunk = wgid / 12;
    int t     = wgid - chunk * 12;               // block-uniform -> s_load
    int n     = chunk * 256 + (int)threadIdx.x;
    if (n >= NN) return;
    const float* xr = xagg + (size_t)n * 192;
    const float* Wt = M2 + (size_t)t * 48 * CO;  // uniform -> s_load

    // stage all inputs: 12 independent dwordx4 in flight, one wait
    float4 xa[12];
    #pragma unroll
    for (int k = 0; k < 3; k++) {
        int tp = t + k - 1;
        if (tp >= 0 && tp < WT) {                // block-uniform branch
            const float4* xs = (const float4*)(xr + tp * 16);
            #pragma unroll
            for (int q = 0; q < 4; q++) xa[k * 4 + q] = xs[q];
        } else {
            #pragma unroll
            for (int q = 0; q < 4; q++) xa[k * 4 + q] = make_float4(0.f, 0.f, 0.f, 0.f);
        }
    }

    float acc[CO];
    #pragma unroll
    for (int co = 0; co < CO; co++) acc[co] = B2[t * CO + co];

    const float* xf = (const float*)xa;
    #pragma unroll
    for (int r = 0; r < 48; r++) {               // static index -> registers
        float a = xf[r];
        const float* wrow = Wt + r * CO;
        #pragma unroll
        for (int co = 0; co < CO; co++)
            acc[co] += a * wrow[co];
    }

    float* o = out + ((size_t)n * WT + t) * CO;
    #pragma unroll
    for (int co = 0; co < CO; co += 4) {
        f32x4 v;
        v.x = acc[co]     >= 0.0f ? acc[co]     : 0.01f * acc[co];
        v.y = acc[co + 1] >= 0.0f ? acc[co + 1] : 0.01f * acc[co + 1];
        v.z = acc[co + 2] >= 0.0f ? acc[co + 2] : 0.01f * acc[co + 2];
        v.w = acc[co + 3] >= 0.0f ? acc[co + 3] : 0.01f * acc[co + 3];
        __builtin_nontemporal_store(v, (f32x4*)(o + co));
    }
}

// ---------------- launch ----------------------------------------------------
extern "C" void kernel_launch(void* const* d_in, const int* in_sizes, int n_in,
                              void* d_out, int out_size, void* d_ws, size_t ws_size,
                              hipStream_t stream) {
    const float* x  = (const float*)d_in[0];
    const int*   A  = (const int*)d_in[1];
    const float* ew = (const float*)d_in[2];
    const float* gw = (const float*)d_in[3];
    const float* gb = (const float*)d_in[4];
    const float* cw = (const float*)d_in[5];
    const float* cb = (const float*)d_in[6];
    float* out = (float*)d_out;
    float* ws  = (float*)d_ws;

    // ws layout (float offsets), every segment a multiple of 32 floats so
    // xagg is 128B-aligned (rows = exactly six 128B lines):
    // [pk 2N (u64)][total 32][rank E][dis N][ds 2N (int2)]
    // [meta 2E (float2)][xTb N*96 (uint)][M2 18432][B2 384][xagg N*192]
    unsigned long long* pk = (unsigned long long*)ws;
    int*      total = (int*)(ws + 2 * NN);
    int*      rank  = (int*)(ws + 2 * NN + 32);
    float*    dis   = ws + 2 * NN + 32 + NE;
    int2*     ds    = (int2*)(ws + 3 * NN + 32 + NE);
    float2*   meta  = (float2*)(ws + 5 * NN + 32 + NE);
    unsigned* xTb   = (unsigned*)(ws + 5 * NN + 32 + 3 * NE);
    float*    M2    = ws + 5 * NN + 32 + 3 * NE + NN * 96;
    float*    B2    = M2 + WT * 3 * CI * CO;
    float*    xagg  = B2 + WT * CO;

    // zero pk + total
    hipMemsetAsync(d_ws, 0, (size_t)(2 * NN + 32) * sizeof(float), stream);

    k_xpose    <<<(NN * 96) / 256, 256, 0, stream>>>(x, xTb);
    k_count    <<<(NE + 255) / 256, 256, 0, stream>>>(A, ew, pk, rank);
    k_dis_alloc<<<(NN + 255) / 256, 256, 0, stream>>>(pk, dis, ds, total);
    k_scatter  <<<(NE + 255) / 256, 256, 0, stream>>>(A, ew, dis, ds, rank, meta);
    k_agg      <<<NN / 4, 256, 0, stream>>>(xTb, ds, dis, meta, xagg);
    k_foldW    <<<(WT * 3 * CI * CO + 255) / 256, 256, 0, stream>>>(gw, cw, M2);
    k_foldB    <<<(WT * CO + 255) / 256, 256, 0, stream>>>(gb, cw, cb, B2);
    // 392 chunks (391 real + 1 pad) x 12 t, %8==0 for the XCD swizzle
    k_out      <<<4704, 256, 0, stream>>>(xagg, M2, B2, out);
}

// Round 7
// 551.566 us; speedup vs baseline: 1.4198x; 1.4198x over previous
//
#include <hip/hip_runtime.h>

#define NN 100000
#define NE 1600000
#define WT 12
#define CI 16
#define CM 32
#define CO 32

#define FXS 33554432.0f   // 2^25 fixed-point scale for deg

// ---- bf16 pack (round-to-nearest-even), 2 channels per uint ---------------
__device__ __forceinline__ unsigned bf16pack(float a, float b) {
    unsigned ua = __float_as_uint(a);
    unsigned ub = __float_as_uint(b);
    ua = (ua + 0x7FFFu + ((ua >> 16) & 1u)) >> 16;
    ub = (ub + 0x7FFFu + ((ub >> 16) & 1u)) >> 16;
    return ua | (ub << 16);
}

// ---------------- K0: transpose x [t][n][ci] -> xTb [n][96 uints] ----------
__global__ void k_xpose(const float* __restrict__ x, unsigned* __restrict__ xTb) {
    int f = blockIdx.x * 256 + threadIdx.x;            // over NN*96
    if (f >= NN * 96) return;
    int n = f / 96;
    int u = f - n * 96;
    int t = u >> 3;
    int p = u & 7;
    const float2* x2 = (const float2*)x;
    float2 v = x2[((size_t)t * NN + n) * 8 + p];
    xTb[f] = bf16pack(v.x, v.y);
}

// ---------------- K1: ONE packed 64-bit atomic per edge --------------------
// pk[c] bits 40+: count; bits 0..39: fixed-point weighted degree (ew * 2^25).
// Returned old value gives this edge's rank within its destination.
__global__ void k_count(const int* __restrict__ A, const float* __restrict__ ew,
                        unsigned long long* __restrict__ pk, int* __restrict__ rank) {
    int e = blockIdx.x * 256 + threadIdx.x;
    if (e >= NE) return;
    int c = A[NE + e];
    unsigned long long fx = (unsigned long long)(ew[e] * FXS + 0.5f);
    unsigned long long old = atomicAdd(&pk[c], (1ull << 40) | fx);
    rank[e] = (int)(old >> 40);
}

// ---------------- K2: dis = rsqrt(deg), segment allocation (wave-scan) -----
// ds[n] = {start, cnt}; dis[n] = deg>0 ? rsqrt(deg) : 0
__global__ void k_dis_alloc(const unsigned long long* __restrict__ pk,
                            float* __restrict__ dis, int2* __restrict__ ds,
                            int* __restrict__ total) {
    int n = blockIdx.x * 256 + threadIdx.x;
    bool valid = (n < NN);
    int c = 0;
    if (valid) {
        unsigned long long v = pk[n];
        c = (int)(v >> 40);
        float d = (float)(v & ((1ull << 40) - 1)) * (1.0f / FXS);
        dis[n] = d > 0.0f ? rsqrtf(d) : 0.0f;
    }
    int lane = threadIdx.x & 63;
    int inc = c;
    #pragma unroll
    for (int o = 1; o < 64; o <<= 1) {
        int v = __shfl_up(inc, o, 64);
        if (lane >= o) inc += v;
    }
    int base = 0;
    if (lane == 63) base = atomicAdd(total, inc);   // one atomic per wave
    base = __shfl(base, 63, 64);
    if (valid) ds[n] = make_int2(base + inc - c, c);
}

// ---------------- K3: atomic-free scatter ----------------------------------
// meta[p] = {src, dis[src]*ew}; dis[dst] applied at end of k_agg instead.
__global__ void k_scatter(const int* __restrict__ A, const float* __restrict__ ew,
                          const float* __restrict__ dis, const int2* __restrict__ ds,
                          const int* __restrict__ rank, float2* __restrict__ meta) {
    int e = blockIdx.x * 256 + threadIdx.x;
    if (e >= NE) return;
    int r = A[e];
    int c = A[NE + e];
    float w = dis[r] * ew[e];
    int p = ds[c].x + rank[e];
    meta[p] = make_float2(__int_as_float(r), w);
}

// ---------------- K4: aggregation, one wave per dst node -------------------
// Lane l<48 loads uint2 -> whole 384B bf16 row in ONE coalesced dwordx2.
// 4 fp32 accs/lane (flat channels 4l..4l+3); dis[node] applied once at end.
__global__ __launch_bounds__(256) void k_agg(const unsigned* __restrict__ xTb,
                      const int2* __restrict__ ds, const float* __restrict__ dis,
                      const float2* __restrict__ meta, float* __restrict__ xagg) {
    int wave = threadIdx.x >> 6;
    int lane = threadIdx.x & 63;
    int node = blockIdx.x * 4 + wave;
    int2 sc = ds[node];
    int s = __builtin_amdgcn_readfirstlane(sc.x);   // force scalar -> s_load meta
    int c = __builtin_amdgcn_readfirstlane(sc.y);
    int li = lane < 48 ? lane : 47;                 // clamp: same cache line, no branch
    float4 acc = make_float4(0.f, 0.f, 0.f, 0.f);
    const float2* mp = meta + s;
    #pragma unroll 4
    for (int i = 0; i < c; i++) {
        float2 m = mp[i];                           // wave-uniform -> scalar load
        int src = __float_as_int(m.x);
        float w = m.y;
        uint2 u = ((const uint2*)(xTb + (size_t)src * 96))[li];
        acc.x += w * __uint_as_float(u.x << 16);
        acc.y += w * __uint_as_float(u.x & 0xFFFF0000u);
        acc.z += w * __uint_as_float(u.y << 16);
        acc.w += w * __uint_as_float(u.y & 0xFFFF0000u);
    }
    float dn = dis[node];
    acc.x *= dn; acc.y *= dn; acc.z *= dn; acc.w *= dn;
    if (lane < 48)
        ((float4*)(xagg + (size_t)node * 192))[lane] = acc;
}

// ---------------- K5a: fold GCN weight into conv weight --------------------
__global__ void k_foldW(const float* __restrict__ gw, const float* __restrict__ cw,
                        float* __restrict__ M2) {
    int i = blockIdx.x * 256 + threadIdx.x;
    if (i >= WT * 3 * CI * CO) return;
    int co = i & 31;
    int rem = i >> 5;            // t*48 + k*16 + ci
    int ci = rem & 15;
    int kidx = rem % 48;
    int k = kidx >> 4;
    int t = rem / 48;
    int tp = t + k - 1;
    float s = 0.0f;
    if (tp >= 0 && tp < WT) {
        for (int cm = 0; cm < CM; cm++)
            s += gw[(tp * CI + ci) * CM + cm] * cw[co * (CM * 3) + cm * 3 + k];
    }
    M2[i] = s;
}

// ---------------- K5b: fold biases -----------------------------------------
__global__ void k_foldB(const float* __restrict__ gb, const float* __restrict__ cw,
                        const float* __restrict__ cb, float* __restrict__ B2) {
    int i = blockIdx.x * 256 + threadIdx.x;
    if (i >= WT * CO) return;
    int co = i & 31;
    int t = i >> 5;
    float s = cb[co];
    for (int k = 0; k < 3; k++) {
        int tp = t + k - 1;
        if (tp < 0 || tp >= WT) continue;
        for (int cm = 0; cm < CM; cm++)
            s += gb[tp * CM + cm] * cw[co * (CM * 3) + cm * 3 + k];
    }
    B2[i] = s;
}

// ---------------- K7: per-(chunk,t) epilogue, XCD-swizzled 1D grid ---------
// Grid = 392 chunks x 12 t = 4704 blocks (%8==0). chunk/t decoded from a
// SWIZZLED block id -> block-uniform -> weights stay s_load (SGPR 112).
// Swizzle: wgid=(bid&7)*588+(bid>>3): each XCD gets a contiguous wgid range
// with t fastest -> the 12 sharers of one 192KB xagg chunk run back-to-back
// on ONE XCD -> re-reads are L2-hits, HBM fetch compulsory (53MB, round 3).
// All 12 xagg float4 loads hoisted into xa[12] BEFORE any FMA (round-3's
// VGPR=40 showed ~2 loads in flight, vmcnt-latency-bound at 102us; staging
// costs ~48 VGPR -> one wait, then a clean 48x32 FMA sweep with weight
// s_loads pipelining underneath).
// Stores are PLAIN float4: round-5's nontemporal stores bypassed L2's
// write-coalescing of the 4x16B-per-thread pattern -> partial-line RMW at
// the memory controller, WRITE_SIZE 161->564MB, k_out 102->335us. L2 must
// absorb and merge the output stream.
__global__ __launch_bounds__(256) void k_out(const float* __restrict__ xagg,
                                             const float* __restrict__ M2,
                                             const float* __restrict__ B2,
                                             float* __restrict__ out) {
    int wgid  = ((int)blockIdx.x & 7) * 588 + ((int)blockIdx.x >> 3);
    int chunk = wgid / 12;
    int t     = wgid - chunk * 12;               // block-uniform -> s_load
    int n     = chunk * 256 + (int)threadIdx.x;
    if (n >= NN) return;
    const float* xr = xagg + (size_t)n * 192;
    const float* Wt = M2 + (size_t)t * 48 * CO;  // uniform -> s_load

    // stage all inputs: 12 independent dwordx4 in flight, one wait
    float4 xa[12];
    #pragma unroll
    for (int k = 0; k < 3; k++) {
        int tp = t + k - 1;
        if (tp >= 0 && tp < WT) {                // block-uniform branch
            const float4* xs = (const float4*)(xr + tp * 16);
            #pragma unroll
            for (int q = 0; q < 4; q++) xa[k * 4 + q] = xs[q];
        } else {
            #pragma unroll
            for (int q = 0; q < 4; q++) xa[k * 4 + q] = make_float4(0.f, 0.f, 0.f, 0.f);
        }
    }

    float acc[CO];
    #pragma unroll
    for (int co = 0; co < CO; co++) acc[co] = B2[t * CO + co];

    const float* xf = (const float*)xa;
    #pragma unroll
    for (int r = 0; r < 48; r++) {               // static index -> registers
        float a = xf[r];
        const float* wrow = Wt + r * CO;
        #pragma unroll
        for (int co = 0; co < CO; co++)
            acc[co] += a * wrow[co];
    }

    float* o = out + ((size_t)n * WT + t) * CO;
    #pragma unroll
    for (int co = 0; co < CO; co += 4) {
        float4 v;
        v.x = acc[co]     >= 0.0f ? acc[co]     : 0.01f * acc[co];
        v.y = acc[co + 1] >= 0.0f ? acc[co + 1] : 0.01f * acc[co + 1];
        v.z = acc[co + 2] >= 0.0f ? acc[co + 2] : 0.01f * acc[co + 2];
        v.w = acc[co + 3] >= 0.0f ? acc[co + 3] : 0.01f * acc[co + 3];
        *(float4*)(o + co) = v;
    }
}

// ---------------- launch ----------------------------------------------------
extern "C" void kernel_launch(void* const* d_in, const int* in_sizes, int n_in,
                              void* d_out, int out_size, void* d_ws, size_t ws_size,
                              hipStream_t stream) {
    const float* x  = (const float*)d_in[0];
    const int*   A  = (const int*)d_in[1];
    const float* ew = (const float*)d_in[2];
    const float* gw = (const float*)d_in[3];
    const float* gb = (const float*)d_in[4];
    const float* cw = (const float*)d_in[5];
    const float* cb = (const float*)d_in[6];
    float* out = (float*)d_out;
    float* ws  = (float*)d_ws;

    // ws layout (float offsets), every segment a multiple of 32 floats so
    // xagg is 128B-aligned (rows = exactly six 128B lines):
    // [pk 2N (u64)][total 32][rank E][dis N][ds 2N (int2)]
    // [meta 2E (float2)][xTb N*96 (uint)][M2 18432][B2 384][xagg N*192]
    unsigned long long* pk = (unsigned long long*)ws;
    int*      total = (int*)(ws + 2 * NN);
    int*      rank  = (int*)(ws + 2 * NN + 32);
    float*    dis   = ws + 2 * NN + 32 + NE;
    int2*     ds    = (int2*)(ws + 3 * NN + 32 + NE);
    float2*   meta  = (float2*)(ws + 5 * NN + 32 + NE);
    unsigned* xTb   = (unsigned*)(ws + 5 * NN + 32 + 3 * NE);
    float*    M2    = ws + 5 * NN + 32 + 3 * NE + NN * 96;
    float*    B2    = M2 + WT * 3 * CI * CO;
    float*    xagg  = B2 + WT * CO;

    // zero pk + total
    hipMemsetAsync(d_ws, 0, (size_t)(2 * NN + 32) * sizeof(float), stream);

    k_xpose    <<<(NN * 96) / 256, 256, 0, stream>>>(x, xTb);
    k_count    <<<(NE + 255) / 256, 256, 0, stream>>>(A, ew, pk, rank);
    k_dis_alloc<<<(NN + 255) / 256, 256, 0, stream>>>(pk, dis, ds, total);
    k_scatter  <<<(NE + 255) / 256, 256, 0, stream>>>(A, ew, dis, ds, rank, meta);
    k_agg      <<<NN / 4, 256, 0, stream>>>(xTb, ds, dis, meta, xagg);
    k_foldW    <<<(WT * 3 * CI * CO + 255) / 256, 256, 0, stream>>>(gw, cw, M2);
    k_foldB    <<<(WT * CO + 255) / 256, 256, 0, stream>>>(gb, cw, cb, B2);
    // 392 chunks (391 real + 1 pad) x 12 t, %8==0 for the XCD swizzle
    k_out      <<<4704, 256, 0, stream>>>(xagg, M2, B2, out);
}